// Round 7
// baseline (9187.666 us; speedup 1.0000x reference)
//
#include <hip/hip_runtime.h>

// ---------------------------------------------------------------------------
// LSTM B=32, S=2048, E=512, H=512 (gates 4H=2048), fp32 in/out.
//   prep_kernel : permuted bias, zero tagged-h buffers + wave-flags, lengths.
//   xproj_gemm  : xp[t][b][n''] bf16 = x @ W_ih^T + bias (split-bf16 MFMA).
//   lstm_rec    : persistent, 64 WGs x 256 thr = two independent 32-WG clubs
//                 (one per batch half). WG = 16 units x 16 batches. W_hh in
//                 VGPRs (bf16 hi/lo split, 3-term MFMA).
//
//   R11: DRAIN-FREE PER-WAVE FLAGS + NARROW TAG RETRY.
//   Cost model (R4..R10): agent-scope LLC RT ~1900cy. R8 (best, 6335us) =
//   3.5 serialized RTs: [h-ack drain][flag hop + detect][bulk stage]+compute.
//   R10's regression was traced to its pre-flag __syncthreads whose implicit
//   vmcnt(0) drained the HBM out-store (~1000cy) ahead of the flag, plus
//   full-width bulk retries. R11 cuts the first RT properly:
//     * per-WAVE flags ([club][wg][wave]): lane0 stores flag right after the
//       wave's 64 h-stores ISSUE (program order; compiler pinned by asm
//       memory clobber). NO drain, NO barrier before the flag.
//     * h entries are 8B {tag=t | packed hi/lo bf16}; consumers verify tags
//       after the flag-gated bulk and retry ONLY stale entries (narrow).
//       Timing gives ~1RT of margin (bulk is serviced >=1RT after
//       flag-visible; data was issued before the flag), tags make it safe.
//     * per-wave INDEPENDENT poll: wave w needs only producer WGs
//       [8w,8w+8) (its K-slice units [128w,128w+128)); polls their 32
//       wave-flags (one 8B atomic load per lane), then goes straight to its
//       private bulk+unpack (LDS quarter is wave-private). Barriers 4 -> 2.
//     * HBM-latency ops (out nt-store, xp nt-prefetch) stay strictly after
//       the flag; the post-reduce barrier drain overlaps the next poll wait.
//   Overwrite safety: unchanged depth-1 induction + strictly-increasing tags
//   per parity (same argument as R9/R10, both of which passed).
//   LDS contents / MFMA order / reduce order bitwise-identical to R8/R10
//   (absmax 0.00390625).
// ---------------------------------------------------------------------------

typedef __attribute__((ext_vector_type(8))) __bf16 bf16x8;
typedef __attribute__((ext_vector_type(8))) short short8;
typedef __attribute__((ext_vector_type(4))) float floatx4;

// ws layout (bytes)
#define XP_OFF    0ull
#define XP_BYTES  (2048ull * 32ull * 2048ull * 2ull)   // 268,435,456
#define ENT_OFF   (XP_OFF + XP_BYTES)                  // [2][32][512] x 8B
#define ENT_BYTES (2ull * 32ull * 512ull * 8ull)       // 262,144
#define BIAS_OFF  (ENT_OFF + ENT_BYTES)
#define FLAG_OFF  (BIAS_OFF + 8192ull)                 // flags[2][32][4] u32
#define WS_NEED   (FLAG_OFF + 1024ull)

// d_out layout (fp32): out[32][2048][1][512], lengths[32], hidden[1][32][512]
#define LEN_OFF_F    33554432
#define HIDDEN_OFF_F 33554464

__device__ inline float sigm(float x) { return 1.f / (1.f + __expf(-x)); }
__device__ inline float tanh_(float x) {
  float e = __expf(-2.f * fabsf(x));
  float r = (1.f - e) / (1.f + e);
  return x >= 0.f ? r : -r;
}

__device__ inline void cvt_hilo8(const float* v, bf16x8& hi, bf16x8& lo) {
#pragma unroll
  for (int i = 0; i < 8; ++i) {
    __bf16 h = (__bf16)v[i];
    hi[i] = h;
    lo[i] = (__bf16)(v[i] - (float)h);
  }
}

__device__ inline float bf16f(unsigned short u) {
  union { unsigned u; float f; } c; c.u = ((unsigned)u) << 16; return c.f;
}

// ---------------------------------------------------------------------------
__global__ __launch_bounds__(256) void prep_kernel(
    const float* __restrict__ bih, const float* __restrict__ bhh,
    const int* __restrict__ len, float* __restrict__ biasp,
    unsigned long long* __restrict__ ent, unsigned* __restrict__ flags,
    float* __restrict__ outf) {
  const int gtid = blockIdx.x * 256 + threadIdx.x;
  if (gtid < 2048) {
    // n'' = ug4*16 + ul*4 + g  ->  W row = g*512 + ug4*4 + ul
    int rowg = (gtid & 3) * 512 + (gtid >> 4) * 4 + ((gtid >> 2) & 3);
    biasp[gtid] = bih[rowg] + bhh[rowg];
  }
  // buf0 tag 0 == "h input for step 0" (h=0); buf1 tag 0 reads as unready.
  for (int i = gtid; i < 32768; i += 16384) ent[i] = 0ull;
  if (gtid < 256) flags[gtid] = 0u;
  if (gtid < 32) outf[LEN_OFF_F + gtid] = (float)len[gtid];
}

// ---------------------------------------------------------------------------
// xp GEMM: M=65536 (b*2048+s), N=2048 (n''), K=512. Tile 64x64, BK=32.
__global__ __launch_bounds__(256) void xproj_gemm(
    const float* __restrict__ x, const float* __restrict__ Wih,
    const float* __restrict__ biasp, __bf16* __restrict__ xp) {
  __shared__ short Ash[64 * 40], Asl[64 * 40], Bsh[64 * 40], Bsl[64 * 40];
  const int tid = threadIdx.x;
  const int w = tid >> 6, lane = tid & 63, ln = lane & 15, kq = lane >> 4;
  const int ntile = blockIdx.x & 31, mtile = blockIdx.x >> 5;
  const int srow = tid >> 2, sseg = tid & 3;

  const size_t a_base = (size_t)(mtile * 64 + srow) * 512 + sseg * 8;
  const int np_s = ntile * 64 + srow;
  const int rowg = (np_s & 3) * 512 + (np_s >> 4) * 4 + ((np_s >> 2) & 3);
  const size_t b_base = (size_t)rowg * 512 + sseg * 8;

  floatx4 acc[4] = {{0,0,0,0},{0,0,0,0},{0,0,0,0},{0,0,0,0}};

  for (int k0 = 0; k0 < 512; k0 += 32) {
    floatx4 a0 = *(const floatx4*)(x + a_base + k0);
    floatx4 a1 = *(const floatx4*)(x + a_base + k0 + 4);
    floatx4 b0 = *(const floatx4*)(Wih + b_base + k0);
    floatx4 b1 = *(const floatx4*)(Wih + b_base + k0 + 4);
    __syncthreads();
    {
      float va[8] = {a0[0],a0[1],a0[2],a0[3],a1[0],a1[1],a1[2],a1[3]};
      bf16x8 hi, lo; cvt_hilo8(va, hi, lo);
      *(short8*)&Ash[srow * 40 + sseg * 8] = __builtin_bit_cast(short8, hi);
      *(short8*)&Asl[srow * 40 + sseg * 8] = __builtin_bit_cast(short8, lo);
      float vb[8] = {b0[0],b0[1],b0[2],b0[3],b1[0],b1[1],b1[2],b1[3]};
      cvt_hilo8(vb, hi, lo);
      *(short8*)&Bsh[srow * 40 + sseg * 8] = __builtin_bit_cast(short8, hi);
      *(short8*)&Bsl[srow * 40 + sseg * 8] = __builtin_bit_cast(short8, lo);
    }
    __syncthreads();
    bf16x8 ah = __builtin_bit_cast(bf16x8, *(const short8*)&Ash[(16 * w + ln) * 40 + kq * 8]);
    bf16x8 al = __builtin_bit_cast(bf16x8, *(const short8*)&Asl[(16 * w + ln) * 40 + kq * 8]);
#pragma unroll
    for (int nt = 0; nt < 4; ++nt) {
      bf16x8 bh = __builtin_bit_cast(bf16x8, *(const short8*)&Bsh[(nt * 16 + ln) * 40 + kq * 8]);
      bf16x8 bl = __builtin_bit_cast(bf16x8, *(const short8*)&Bsl[(nt * 16 + ln) * 40 + kq * 8]);
      acc[nt] = __builtin_amdgcn_mfma_f32_16x16x32_bf16(ah, bh, acc[nt], 0, 0, 0);
      acc[nt] = __builtin_amdgcn_mfma_f32_16x16x32_bf16(al, bh, acc[nt], 0, 0, 0);
      acc[nt] = __builtin_amdgcn_mfma_f32_16x16x32_bf16(ah, bl, acc[nt], 0, 0, 0);
    }
  }
#pragma unroll
  for (int nt = 0; nt < 4; ++nt) {
    const int npg = ntile * 64 + nt * 16 + ln;
    const float bs = biasp[npg];
#pragma unroll
    for (int r = 0; r < 4; ++r) {
      const int m = mtile * 64 + w * 16 + kq * 4 + r;
      const int s = m & 2047, b = m >> 11;
      xp[(size_t)(s * 32 + b) * 2048 + npg] = (__bf16)(acc[nt][r] + bs);
    }
  }
}

// ---------------------------------------------------------------------------
__global__ __launch_bounds__(256, 1) void lstm_rec(
    const float* __restrict__ Whh, const int* __restrict__ lengths,
    const __bf16* __restrict__ xp, float* __restrict__ out,
    float* __restrict__ hid, unsigned long long* __restrict__ ent,
    unsigned* __restrict__ flags) {
  __shared__ short Hh[16 * 512];       // [m][k] bf16 hi, xor-swizzled granules
  __shared__ short Hl[16 * 512];
  __shared__ float Part[4 * 1088];     // [wave][nt(272 pad)][m][n]

  const int tid = threadIdx.x;
  const int w = tid >> 6, lane = tid & 63, ln = lane & 15, kq = lane >> 4;
  const int bh = blockIdx.x >> 5;      // batch half
  const int ug = blockIdx.x & 31;      // 16-unit group
  const int b0 = bh * 16;

  // Persistent W_hh frags. Tile nt, lane ln: g=ln&3, ul=ln>>2,
  // unit = ug*16 + nt*4 + ul, row = g*512 + unit. K-slice of wave w.
  bf16x8 whi[4][4], wlo[4][4];
#pragma unroll
  for (int nt = 0; nt < 4; ++nt) {
    const int rowg = (ln & 3) * 512 + (ug * 4 + nt) * 4 + (ln >> 2);
#pragma unroll
    for (int kc = 0; kc < 4; ++kc) {
      const int k = w * 128 + kc * 32 + kq * 8;
      floatx4 f0 = *(const floatx4*)(Whh + (size_t)rowg * 512 + k);
      floatx4 f1 = *(const floatx4*)(Whh + (size_t)rowg * 512 + k + 4);
      float v[8] = {f0[0],f0[1],f0[2],f0[3],f1[0],f1[1],f1[2],f1[3]};
      cvt_hilo8(v, whi[nt][kc], wlo[nt][kc]);
    }
  }

  // Elementwise ownership: 1 (batch,unit) per thread.
  const int m_e = tid >> 4, ue = tid & 15;
  const int b_e = b0 + m_e, u_e = ug * 16 + ue;
  const int lenb = lengths[b_e];
  float cst = 0.f, hcap = 0.f;

  // xp: this thread's 4 gate pre-acts are 8B contiguous, NONTEMPORAL stream.
  const __bf16* xpb = xp + (size_t)b_e * 2048 + ug * 64 + (ue >> 2) * 16 + (ue & 3) * 4;
  unsigned long long xpcur =
      __builtin_nontemporal_load((const unsigned long long*)xpb);  // t = 0
  unsigned long long xpnext;

  // publish: one tagged 8B entry; one flag per (wg,wave).
  unsigned long long* pub = ent + (size_t)b_e * 512 + u_e;
  unsigned* myflag = flags + (bh * 32 + ug) * 4 + w;
  // poll: wave w needs producer WGs [8w,8w+8) x 4 waves = 32 flags = 16
  // u64 pairs; 4 lanes per pair. lane bits [5:3]=wg offset, [2]=pair.
  const unsigned long long* pollq = (const unsigned long long*)(
      flags + bh * 128 + (8 * w + (lane >> 3)) * 4 + ((lane >> 2) & 1) * 2);

  for (int t = 0; t < 2048; ++t) {
    // ---- per-wave independent poll of this wave's 8 producers ----
    if (t > 0) {
      for (;;) {
        unsigned long long f = __hip_atomic_load(pollq, __ATOMIC_RELAXED,
                                                 __HIP_MEMORY_SCOPE_AGENT);
        bool ok = ((unsigned)f >= (unsigned)t) &&
                  ((unsigned)(f >> 32) >= (unsigned)t);
        if (__ballot(!ok) == 0ull) break;
        __builtin_amdgcn_s_sleep(1);
      }
    }
    // ---- bulk tagged stage of this wave's K-slice (units 2tid, 2tid+1
    // for all 16 club batches); narrow per-entry retry (expected never). ----
    const unsigned long long* sb =
        ent + (size_t)(t & 1) * 16384 + (size_t)b0 * 512 + 2 * tid;
    unsigned long long e0[16], e1[16];
#pragma unroll
    for (int k = 0; k < 16; ++k) {
      e0[k] = __hip_atomic_load(sb + (size_t)k * 512, __ATOMIC_RELAXED,
                                __HIP_MEMORY_SCOPE_AGENT);
      e1[k] = __hip_atomic_load(sb + (size_t)k * 512 + 1, __ATOMIC_RELAXED,
                                __HIP_MEMORY_SCOPE_AGENT);
    }
#pragma unroll
    for (int k = 0; k < 16; ++k) {
      while ((unsigned)(e0[k] >> 32) != (unsigned)t)
        e0[k] = __hip_atomic_load(sb + (size_t)k * 512, __ATOMIC_RELAXED,
                                  __HIP_MEMORY_SCOPE_AGENT);
      while ((unsigned)(e1[k] >> 32) != (unsigned)t)
        e1[k] = __hip_atomic_load(sb + (size_t)k * 512 + 1, __ATOMIC_RELAXED,
                                  __HIP_MEMORY_SCOPE_AGENT);
    }
    // ---- unpack hi/lo -> swizzled LDS planes. Wave-private quarter
    // (granules [16w,16w+16)); its MFMA reads only this quarter -> no
    // barrier between unpack and MFMA. ----
    {
      const int g = tid >> 2;  // 8-unit granule of units (tid*2, tid*2+1)
#pragma unroll
      for (int k = 0; k < 16; ++k) {
        const unsigned w0 = (unsigned)e0[k], w1 = (unsigned)e1[k];
        const int d = k * 512 + ((g ^ (k & 7)) * 8) + (tid & 3) * 2;
        *(unsigned*)&Hh[d] = (w0 >> 16) | (w1 & 0xffff0000u);
        *(unsigned*)&Hl[d] = (w0 & 0xffffu) | (w1 << 16);
      }
    }
    // ---- MFMA: M=16 batches x N=16 gate-rows x 4 tiles, wave K-slice ----
    floatx4 acc[4] = {{0,0,0,0},{0,0,0,0},{0,0,0,0},{0,0,0,0}};
#pragma unroll
    for (int kc = 0; kc < 4; ++kc) {
      const int g = w * 16 + kc * 4 + kq;
      const int d = ln * 512 + ((g ^ (ln & 7)) * 8);
      bf16x8 ah = __builtin_bit_cast(bf16x8, *(const short8*)&Hh[d]);
      bf16x8 al = __builtin_bit_cast(bf16x8, *(const short8*)&Hl[d]);
#pragma unroll
      for (int nt = 0; nt < 4; ++nt) {
        acc[nt] = __builtin_amdgcn_mfma_f32_16x16x32_bf16(ah, whi[nt][kc], acc[nt], 0, 0, 0);
        acc[nt] = __builtin_amdgcn_mfma_f32_16x16x32_bf16(al, whi[nt][kc], acc[nt], 0, 0, 0);
        acc[nt] = __builtin_amdgcn_mfma_f32_16x16x32_bf16(ah, wlo[nt][kc], acc[nt], 0, 0, 0);
      }
    }
#pragma unroll
    for (int nt = 0; nt < 4; ++nt)
#pragma unroll
      for (int r4 = 0; r4 < 4; ++r4)
        Part[w * 1088 + nt * 272 + (kq * 4 + r4) * 16 + ln] = acc[nt][r4];
    __syncthreads();   // Part stores (wave-private) -> cross-wave reduce
    // ---- reduce + gates + state (all 256 threads, one (b,u) each) ----
    {
      const int pb = (ue >> 2) * 272 + m_e * 16 + (ue & 3) * 4;
      floatx4 p0 = *(const floatx4*)&Part[pb];
      floatx4 p1 = *(const floatx4*)&Part[1088 + pb];
      floatx4 p2 = *(const floatx4*)&Part[2176 + pb];
      floatx4 p3 = *(const floatx4*)&Part[3264 + pb];
      const float xg0 = bf16f((unsigned short)(xpcur & 0xffffu));
      const float xg1 = bf16f((unsigned short)((xpcur >> 16) & 0xffffu));
      const float xg2 = bf16f((unsigned short)((xpcur >> 32) & 0xffffu));
      const float xg3 = bf16f((unsigned short)(xpcur >> 48));
      const float pi = xg0 + p0[0] + p1[0] + p2[0] + p3[0];
      const float pf = xg1 + p0[1] + p1[1] + p2[1] + p3[1];
      const float pg = xg2 + p0[2] + p1[2] + p2[2] + p3[2];
      const float po = xg3 + p0[3] + p1[3] + p2[3] + p3[3];
      const float gi_ = sigm(pi), gf = sigm(pf), gg = tanh_(pg), go = sigm(po);
      cst = gf * cst + gi_ * gg;
      const float hv = go * tanh_(cst);
      // publish {tag=t+1 | packed hi/lo}: fire-and-forget agent store,
      // then THIS WAVE's flag (program order pinned; no drain).
      const __bf16 hb = (__bf16)hv;
      const __bf16 lb = (__bf16)(hv - (float)hb);
      const unsigned pk =
          ((unsigned)__builtin_bit_cast(unsigned short, hb) << 16) |
          (unsigned)__builtin_bit_cast(unsigned short, lb);
      __hip_atomic_store(pub + (size_t)((t + 1) & 1) * 16384,
                         ((unsigned long long)(unsigned)(t + 1) << 32) |
                             (unsigned long long)pk,
                         __ATOMIC_RELAXED, __HIP_MEMORY_SCOPE_AGENT);
      asm volatile("" ::: "memory");  // pin flag AFTER h stores (issue order)
      if ((tid & 63) == 0)
        __hip_atomic_store(myflag, (unsigned)(t + 1), __ATOMIC_RELAXED,
                           __HIP_MEMORY_SCOPE_AGENT);
      // off-path (after flag): out nt store, hid in a register
      __builtin_nontemporal_store((t < lenb) ? hv : 0.f,
                                  &out[((size_t)b_e * 2048 + t) * 512 + u_e]);
      if (t == lenb - 1) hcap = hv;
    }
    __syncthreads();   // Part reads done -> next iteration may overwrite
    // xp prefetch for t+1, off the critical path at the loop tail.
    {
      const int tn = (t + 1 < 2048) ? t + 1 : 2047;
      xpnext = __builtin_nontemporal_load(
          (const unsigned long long*)(xpb + (size_t)tn * 65536));
    }
    xpcur = xpnext;
  }
  hid[b_e * 512 + u_e] = hcap;
}

// ---------------------------------------------------------------------------
extern "C" void kernel_launch(void* const* d_in, const int* in_sizes, int n_in,
                              void* d_out, int out_size, void* d_ws, size_t ws_size,
                              hipStream_t stream) {
  const float* x = (const float*)d_in[0];
  const int* lengths = (const int*)d_in[1];
  const float* Wih = (const float*)d_in[2];
  const float* Whh = (const float*)d_in[3];
  const float* bih = (const float*)d_in[4];
  const float* bhh = (const float*)d_in[5];
  float* outf = (float*)d_out;
  char* ws = (char*)d_ws;
  if (ws_size < WS_NEED) return;

  float* biasp = (float*)(ws + BIAS_OFF);
  __bf16* xp = (__bf16*)(ws + XP_OFF);
  unsigned long long* ent = (unsigned long long*)(ws + ENT_OFF);
  unsigned* flags = (unsigned*)(ws + FLAG_OFF);

  prep_kernel<<<64, 256, 0, stream>>>(bih, bhh, lengths, biasp, ent, flags,
                                      outf);
  xproj_gemm<<<32768, 256, 0, stream>>>(x, Wih, biasp, xp);
  lstm_rec<<<64, 256, 0, stream>>>(Whh, lengths, xp, outf,
                                   outf + HIDDEN_OFF_F, ent, flags);
}

// Round 8
// 8803.328 us; speedup vs baseline: 1.0437x; 1.0437x over previous
//
#include <hip/hip_runtime.h>

// ---------------------------------------------------------------------------
// LSTM B=32, S=2048, E=512, H=512 (gates 4H=2048), fp32 in/out.
//   prep_kernel : permuted bias, zero h planes + flags, lengths->floats.
//   xproj_gemm  : xp[t][b][n''] bf16 = x @ W_ih^T + bias (split-bf16 MFMA).
//   lstm_rec    : persistent. R12: CLUB RESHAPE 32x256 -> 16x512.
//     Evidence R4..R11: staging transaction count / LLC line sharing / club
//     fan-in dominate (every 8B-entry variant cost +1000-1800cy/step vs 4B).
//     R12 keeps R8's proven protocol EXACTLY (4B packed entries, publish ->
//     vmcnt(0) drain -> barrier -> flag; flag-gated consumer; nt xp/out
//     streams; prefetch after flag) and halves all three structural costs:
//       * 16 WGs x 512 thr per club (32 units x 16 batches per WG, 8 waves).
//       * wave w owns K-slice units [64w,64w+64): stages 8x8B atomic loads
//         per thread (was 16), unpacks into wave-PRIVATE LDS granules
//         [8w,8w+8), goes straight to MFMA -- no pre-staging or post-unpack
//         barrier. Barriers/step: 2.
//       * per-wave poll of 16 flags (one 64B line), waves start staging
//         independently.
//       * club staging traffic 1MB -> 512KB/step; 16 readers/line (was 32).
//     Per-wave MFMA work unchanged (8nt x 2kc x 3 = 48); W_hh per thread
//     unchanged (128 VGPRs); reduce now sums 8 K-partials of K=64.
// ---------------------------------------------------------------------------

typedef __attribute__((ext_vector_type(8))) __bf16 bf16x8;
typedef __attribute__((ext_vector_type(8))) short short8;
typedef __attribute__((ext_vector_type(4))) float floatx4;

// ws layout (bytes)
#define XP_OFF   0ull
#define XP_BYTES (2048ull * 32ull * 2048ull * 2ull)   // 268,435,456
#define HPK_OFF  (XP_OFF + XP_BYTES)                  // 2 bufs x 32x512 dwords
#define HPK_BYTES (2ull * 16384ull * 4ull)
#define BIAS_OFF (HPK_OFF + HPK_BYTES)
#define FLAG_OFF (BIAS_OFF + 8192ull)                 // flags[2][16] dwords
#define WS_NEED  (FLAG_OFF + 128ull)

// d_out layout (fp32): out[32][2048][1][512], lengths[32], hidden[1][32][512]
#define LEN_OFF_F    33554432
#define HIDDEN_OFF_F 33554464

__device__ inline float sigm(float x) { return 1.f / (1.f + __expf(-x)); }
__device__ inline float tanh_(float x) {
  float e = __expf(-2.f * fabsf(x));
  float r = (1.f - e) / (1.f + e);
  return x >= 0.f ? r : -r;
}

__device__ inline void cvt_hilo8(const float* v, bf16x8& hi, bf16x8& lo) {
#pragma unroll
  for (int i = 0; i < 8; ++i) {
    __bf16 h = (__bf16)v[i];
    hi[i] = h;
    lo[i] = (__bf16)(v[i] - (float)h);
  }
}

__device__ inline float bf16f(unsigned short u) {
  union { unsigned u; float f; } c; c.u = ((unsigned)u) << 16; return c.f;
}

// ---------------------------------------------------------------------------
__global__ __launch_bounds__(256) void prep_kernel(
    const float* __restrict__ bih, const float* __restrict__ bhh,
    const int* __restrict__ len, float* __restrict__ biasp,
    unsigned* __restrict__ hpk, unsigned* __restrict__ flags,
    float* __restrict__ outf) {
  const int tid = threadIdx.x;
  for (int i = tid; i < 2048; i += 256) {
    // n'' = ug4*16 + ul*4 + g  ->  W row = g*512 + ug4*4 + ul
    int rowg = (i & 3) * 512 + (i >> 4) * 4 + ((i >> 2) & 3);
    biasp[i] = bih[rowg] + bhh[rowg];
  }
  for (int i = tid; i < 32768; i += 256) hpk[i] = 0u;
  if (tid < 32) flags[tid] = 0u;
  if (tid < 32) outf[LEN_OFF_F + tid] = (float)len[tid];
}

// ---------------------------------------------------------------------------
// xp GEMM: M=65536 (b*2048+s), N=2048 (n''), K=512. Tile 64x64, BK=32.
__global__ __launch_bounds__(256) void xproj_gemm(
    const float* __restrict__ x, const float* __restrict__ Wih,
    const float* __restrict__ biasp, __bf16* __restrict__ xp) {
  __shared__ short Ash[64 * 40], Asl[64 * 40], Bsh[64 * 40], Bsl[64 * 40];
  const int tid = threadIdx.x;
  const int w = tid >> 6, lane = tid & 63, ln = lane & 15, kq = lane >> 4;
  const int ntile = blockIdx.x & 31, mtile = blockIdx.x >> 5;
  const int srow = tid >> 2, sseg = tid & 3;

  const size_t a_base = (size_t)(mtile * 64 + srow) * 512 + sseg * 8;
  const int np_s = ntile * 64 + srow;
  const int rowg = (np_s & 3) * 512 + (np_s >> 4) * 4 + ((np_s >> 2) & 3);
  const size_t b_base = (size_t)rowg * 512 + sseg * 8;

  floatx4 acc[4] = {{0,0,0,0},{0,0,0,0},{0,0,0,0},{0,0,0,0}};

  for (int k0 = 0; k0 < 512; k0 += 32) {
    floatx4 a0 = *(const floatx4*)(x + a_base + k0);
    floatx4 a1 = *(const floatx4*)(x + a_base + k0 + 4);
    floatx4 b0 = *(const floatx4*)(Wih + b_base + k0);
    floatx4 b1 = *(const floatx4*)(Wih + b_base + k0 + 4);
    __syncthreads();
    {
      float va[8] = {a0[0],a0[1],a0[2],a0[3],a1[0],a1[1],a1[2],a1[3]};
      bf16x8 hi, lo; cvt_hilo8(va, hi, lo);
      *(short8*)&Ash[srow * 40 + sseg * 8] = __builtin_bit_cast(short8, hi);
      *(short8*)&Asl[srow * 40 + sseg * 8] = __builtin_bit_cast(short8, lo);
      float vb[8] = {b0[0],b0[1],b0[2],b0[3],b1[0],b1[1],b1[2],b1[3]};
      cvt_hilo8(vb, hi, lo);
      *(short8*)&Bsh[srow * 40 + sseg * 8] = __builtin_bit_cast(short8, hi);
      *(short8*)&Bsl[srow * 40 + sseg * 8] = __builtin_bit_cast(short8, lo);
    }
    __syncthreads();
    bf16x8 ah = __builtin_bit_cast(bf16x8, *(const short8*)&Ash[(16 * w + ln) * 40 + kq * 8]);
    bf16x8 al = __builtin_bit_cast(bf16x8, *(const short8*)&Asl[(16 * w + ln) * 40 + kq * 8]);
#pragma unroll
    for (int nt = 0; nt < 4; ++nt) {
      bf16x8 bh = __builtin_bit_cast(bf16x8, *(const short8*)&Bsh[(nt * 16 + ln) * 40 + kq * 8]);
      bf16x8 bl = __builtin_bit_cast(bf16x8, *(const short8*)&Bsl[(nt * 16 + ln) * 40 + kq * 8]);
      acc[nt] = __builtin_amdgcn_mfma_f32_16x16x32_bf16(ah, bh, acc[nt], 0, 0, 0);
      acc[nt] = __builtin_amdgcn_mfma_f32_16x16x32_bf16(al, bh, acc[nt], 0, 0, 0);
      acc[nt] = __builtin_amdgcn_mfma_f32_16x16x32_bf16(ah, bl, acc[nt], 0, 0, 0);
    }
  }
#pragma unroll
  for (int nt = 0; nt < 4; ++nt) {
    const int npg = ntile * 64 + nt * 16 + ln;
    const float bs = biasp[npg];
#pragma unroll
    for (int r = 0; r < 4; ++r) {
      const int m = mtile * 64 + w * 16 + kq * 4 + r;
      const int s = m & 2047, b = m >> 11;
      xp[(size_t)(s * 32 + b) * 2048 + npg] = (__bf16)(acc[nt][r] + bs);
    }
  }
}

// ---------------------------------------------------------------------------
// 32 WGs x 512 thr. WG = 32 units x 16 batches; wave w = K-slice [64w,64w+64).
__global__ __launch_bounds__(512, 2) void lstm_rec(
    const float* __restrict__ Whh, const int* __restrict__ lengths,
    const __bf16* __restrict__ xp, float* __restrict__ out,
    float* __restrict__ hid, unsigned* __restrict__ hpk,
    unsigned* __restrict__ flags) {
  __shared__ short Hh[16 * 512];       // [batch][K-unit] bf16 hi, swizzled
  __shared__ short Hl[16 * 512];
  __shared__ float Part[8 * 2176];     // [wave][nt(272 pad)][m][n]

  const int tid = threadIdx.x;
  const int w = tid >> 6, lane = tid & 63, ln = lane & 15, kq = lane >> 4;
  const int bh = blockIdx.x >> 4;      // batch half (club)
  const int ug = blockIdx.x & 15;      // 32-unit group
  const int b0 = bh * 16;

  // Persistent W_hh frags. Wave w: rows = all 128 gate-rows of this WG
  // (8 nt tiles), K = units [64w, 64w+64) (2 kc chunks of 32).
  // Tile nt, lane ln: gate g=ln&3, ul=ln>>2, unit = ug*32 + nt*4 + ul,
  // W row = g*512 + unit.
  bf16x8 whi[8][2], wlo[8][2];
#pragma unroll
  for (int nt = 0; nt < 8; ++nt) {
    const int rowg = (ln & 3) * 512 + ug * 32 + nt * 4 + (ln >> 2);
#pragma unroll
    for (int kc = 0; kc < 2; ++kc) {
      const int k = w * 64 + kc * 32 + kq * 8;
      floatx4 f0 = *(const floatx4*)(Whh + (size_t)rowg * 512 + k);
      floatx4 f1 = *(const floatx4*)(Whh + (size_t)rowg * 512 + k + 4);
      float v[8] = {f0[0],f0[1],f0[2],f0[3],f1[0],f1[1],f1[2],f1[3]};
      cvt_hilo8(v, whi[nt][kc], wlo[nt][kc]);
    }
  }

  // Elementwise ownership: 1 (batch,unit) per thread (16 x 32 = 512).
  const int m_e = tid >> 5, ue = tid & 31;
  const int b_e = b0 + m_e, u_e = ug * 32 + ue;
  const int lenb = lengths[b_e];
  float cst = 0.f, hcap = 0.f;

  // xp: 4 gate pre-acts contiguous (8B), NONTEMPORAL stream.
  const __bf16* xpb =
      xp + (size_t)b_e * 2048 + (u_e >> 2) * 16 + (u_e & 3) * 4;
  unsigned long long xpcur =
      __builtin_nontemporal_load((const unsigned long long*)xpb);  // t = 0
  unsigned long long xpnext;

  unsigned* myflag = flags + bh * 16 + ug;
  const unsigned* pollp = flags + bh * 16 + (lane & 15);

  // Staging: lane handles units {u0, u0+1} for batches [bst, bst+8).
  const int u0 = w * 64 + 2 * (lane & 31);
  const int bst = 8 * (lane >> 5);
  const int gstg = u0 >> 3;            // LDS granule (in [8w, 8w+8))

  for (int t = 0; t < 2048; ++t) {
    // ---- per-wave poll of the club's 16 WG flags (one 64B line); each
    // wave proceeds independently once its producers are visible. ----
    if (t > 0) {
      for (;;) {
        unsigned f = (lane < 16)
                         ? __hip_atomic_load(pollp, __ATOMIC_RELAXED,
                                             __HIP_MEMORY_SCOPE_AGENT)
                         : (unsigned)t;
        if (__ballot(f < (unsigned)t) == 0ull) break;
        __builtin_amdgcn_s_sleep(1);
      }
    }
    // ---- stage this wave's K-slice: 8 x 8B agent-atomic loads/thread ----
    const unsigned long long* sb = (const unsigned long long*)(
        hpk + (size_t)(t & 1) * 16384 + (size_t)(b0 + bst) * 512 + u0);
    unsigned long long e[8];
#pragma unroll
    for (int j = 0; j < 8; ++j)
      e[j] = __hip_atomic_load(sb + (size_t)j * 256, __ATOMIC_RELAXED,
                               __HIP_MEMORY_SCOPE_AGENT);
    // ---- unpack hi/lo -> wave-PRIVATE LDS granules [8w,8w+8) ----
#pragma unroll
    for (int j = 0; j < 8; ++j) {
      const int k = bst + j;
      const unsigned w0 = (unsigned)e[j], w1 = (unsigned)(e[j] >> 32);
      const int d = k * 512 + ((gstg ^ (k & 7)) * 8) + (u0 & 7);
      *(unsigned*)&Hh[d] = (w0 >> 16) | (w1 & 0xffff0000u);
      *(unsigned*)&Hl[d] = (w0 & 0xffffu) | (w1 << 16);
    }
    // ---- MFMA: M=16 batches x N=128 gate-rows (8 nt) x K=64 (2 kc).
    // Reads only this wave's granules -> no barrier after unpack. ----
    floatx4 acc[8] = {{0,0,0,0},{0,0,0,0},{0,0,0,0},{0,0,0,0},
                      {0,0,0,0},{0,0,0,0},{0,0,0,0},{0,0,0,0}};
#pragma unroll
    for (int kc = 0; kc < 2; ++kc) {
      const int g = 8 * w + kc * 4 + kq;
      const int d = ln * 512 + ((g ^ (ln & 7)) * 8);
      bf16x8 ah = __builtin_bit_cast(bf16x8, *(const short8*)&Hh[d]);
      bf16x8 al = __builtin_bit_cast(bf16x8, *(const short8*)&Hl[d]);
#pragma unroll
      for (int nt = 0; nt < 8; ++nt) {
        acc[nt] = __builtin_amdgcn_mfma_f32_16x16x32_bf16(ah, whi[nt][kc], acc[nt], 0, 0, 0);
        acc[nt] = __builtin_amdgcn_mfma_f32_16x16x32_bf16(al, whi[nt][kc], acc[nt], 0, 0, 0);
        acc[nt] = __builtin_amdgcn_mfma_f32_16x16x32_bf16(ah, wlo[nt][kc], acc[nt], 0, 0, 0);
      }
    }
#pragma unroll
    for (int nt = 0; nt < 8; ++nt)
#pragma unroll
      for (int r4 = 0; r4 < 4; ++r4)
        Part[(w * 8 + nt) * 272 + (kq * 4 + r4) * 16 + ln] = acc[nt][r4];
    __syncthreads();   // Part complete -> cross-wave reduce
    // ---- reduce (8 K-partials) + gates + state ----
    {
      const int pb = (ue >> 2) * 272 + m_e * 16 + (ue & 3) * 4;
      float s0 = 0.f, s1 = 0.f, s2 = 0.f, s3 = 0.f;
#pragma unroll
      for (int wv = 0; wv < 8; ++wv) {
        floatx4 p = *(const floatx4*)&Part[wv * 2176 + pb];
        s0 += p[0]; s1 += p[1]; s2 += p[2]; s3 += p[3];
      }
      const float xg0 = bf16f((unsigned short)(xpcur & 0xffffu));
      const float xg1 = bf16f((unsigned short)((xpcur >> 16) & 0xffffu));
      const float xg2 = bf16f((unsigned short)((xpcur >> 32) & 0xffffu));
      const float xg3 = bf16f((unsigned short)(xpcur >> 48));
      const float gi_ = sigm(xg0 + s0), gf = sigm(xg1 + s1);
      const float gg = tanh_(xg2 + s2), go = sigm(xg3 + s3);
      cst = gf * cst + gi_ * gg;
      const float hv = go * tanh_(cst);
      // publish h (packed hi/lo, 4B) to the other parity buffer
      const __bf16 hb = (__bf16)hv;
      const __bf16 lb = (__bf16)(hv - (float)hb);
      const unsigned pk =
          ((unsigned)__builtin_bit_cast(unsigned short, hb) << 16) |
          (unsigned)__builtin_bit_cast(unsigned short, lb);
      __hip_atomic_store(hpk + (size_t)((t + 1) & 1) * 16384 +
                             (size_t)b_e * 512 + u_e,
                         pk, __ATOMIC_RELAXED, __HIP_MEMORY_SCOPE_AGENT);
      asm volatile("s_waitcnt vmcnt(0)" ::: "memory");  // h store drained
      __syncthreads();                                  // ...by ALL waves
      if (tid == 0)
        __hip_atomic_store(myflag, (unsigned)(t + 1), __ATOMIC_RELAXED,
                           __HIP_MEMORY_SCOPE_AGENT);
      // off-path (after flag): out nt store; hid kept in a register
      __builtin_nontemporal_store((t < lenb) ? hv : 0.f,
                                  &out[((size_t)b_e * 2048 + t) * 512 + u_e]);
      if (t == lenb - 1) hcap = hv;
    }
    // xp prefetch for t+1, off the critical path at the loop tail.
    {
      const int tn = (t + 1 < 2048) ? t + 1 : 2047;
      xpnext = __builtin_nontemporal_load(
          (const unsigned long long*)(xpb + (size_t)tn * 65536));
    }
    xpcur = xpnext;
  }
  hid[b_e * 512 + u_e] = hcap;
}

// ---------------------------------------------------------------------------
extern "C" void kernel_launch(void* const* d_in, const int* in_sizes, int n_in,
                              void* d_out, int out_size, void* d_ws, size_t ws_size,
                              hipStream_t stream) {
  const float* x = (const float*)d_in[0];
  const int* lengths = (const int*)d_in[1];
  const float* Wih = (const float*)d_in[2];
  const float* Whh = (const float*)d_in[3];
  const float* bih = (const float*)d_in[4];
  const float* bhh = (const float*)d_in[5];
  float* outf = (float*)d_out;
  char* ws = (char*)d_ws;
  if (ws_size < WS_NEED) return;

  float* biasp = (float*)(ws + BIAS_OFF);
  __bf16* xp = (__bf16*)(ws + XP_OFF);
  unsigned* hpk = (unsigned*)(ws + HPK_OFF);
  unsigned* flags = (unsigned*)(ws + FLAG_OFF);

  prep_kernel<<<1, 256, 0, stream>>>(bih, bhh, lengths, biasp, hpk, flags, outf);
  xproj_gemm<<<32768, 256, 0, stream>>>(x, Wih, biasp, xp);
  // 32 WGs x 512 thr = two 16-WG clubs (one per batch half).
  lstm_rec<<<32, 512, 0, stream>>>(Whh, lengths, xp, outf,
                                   outf + HIDDEN_OFF_F, hpk, flags);
}